// Round 3
// baseline (371.924 us; speedup 1.0000x reference)
//
#include <hip/hip_runtime.h>

// BatchNorm2d training-mode forward, fp32, NCHW.
// B=64, C=256, H=56, W=56. Layout: idx = ((b*C + c)*H + h)*W + w.
// Plane (b,c) is contiguous HW=3136 floats => 784 float4.

#define EPS 1e-5f
constexpr int B_ = 64;
constexpr int C_ = 256;
constexpr int HW_ = 56 * 56;            // 3136
constexpr int HW4_ = HW_ / 4;           // 784
constexpr int NPC_ = B_ * HW_;          // 200704 elements per channel
constexpr int PB_ = 8;                  // planes (b-values) summed per stats block
constexpr int NB_ = B_ / PB_;           // 8 partial groups per channel
constexpr unsigned int TOTAL4_ = (unsigned int)B_ * C_ * HW4_;  // 12,845,056 float4s

typedef float vfloat4 __attribute__((ext_vector_type(4)));  // clang vector: OK for nontemporal builtins

// ---------------- Kernel 1: per-(channel, b-group) partial sum / sumsq ----------------
// grid = C_ * NB_ = 2048 blocks. Block sums PB_=8 planes of ONE channel, so the
// 12-shuffle+LDS reduction is amortized over 8*784/256 = 24.5 float4 loads/thread.
__global__ void __launch_bounds__(256) bn_stats(const float* __restrict__ x,
                                                float* __restrict__ psum,
                                                float* __restrict__ psumsq) {
    const int c  = blockIdx.x & (C_ - 1);   // consecutive blocks -> consecutive planes
    const int bg = blockIdx.x >> 8;         // C_ == 256

    float s = 0.f, ss = 0.f;
    for (int p = 0; p < PB_; ++p) {
        const int plane = (bg * PB_ + p) * C_ + c;
        const vfloat4* xp = (const vfloat4*)(x + (size_t)plane * HW_);
        for (int i = threadIdx.x; i < HW4_; i += 256) {
            vfloat4 v = xp[i];
            s  += v.x + v.y + v.z + v.w;
            ss += v.x * v.x + v.y * v.y + v.z * v.z + v.w * v.w;
        }
    }

    for (int off = 32; off > 0; off >>= 1) {
        s  += __shfl_down(s, off);
        ss += __shfl_down(ss, off);
    }
    __shared__ float ls[8];
    const int wave = threadIdx.x >> 6;
    const int lane = threadIdx.x & 63;
    if (lane == 0) { ls[wave] = s; ls[4 + wave] = ss; }
    __syncthreads();
    if (threadIdx.x == 0) {
        psum[c * NB_ + bg]   = ls[0] + ls[1] + ls[2] + ls[3];
        psumsq[c * NB_ + bg] = ls[4] + ls[5] + ls[6] + ls[7];
    }
}

// ---------------- Kernel 2: per-channel finalize -> scale/shift ----------------
// grid = C_/64 = 4 blocks x 64 threads; one thread per channel, no shuffles.
__global__ void __launch_bounds__(64) bn_finalize(const float* __restrict__ psum,
                                                  const float* __restrict__ psumsq,
                                                  const float* __restrict__ gamma,
                                                  const float* __restrict__ beta,
                                                  float* __restrict__ scale,
                                                  float* __restrict__ shift) {
    const int c = blockIdx.x * 64 + threadIdx.x;
    float s = 0.f, ss = 0.f;
    for (int j = 0; j < NB_; ++j) {
        s  += psum[c * NB_ + j];
        ss += psumsq[c * NB_ + j];
    }
    const float invN = 1.0f / (float)NPC_;
    const float mean = s * invN;
    const float var  = ss * invN - mean * mean;
    const float sc   = gamma[c] * rsqrtf(var + EPS);
    scale[c] = sc;
    shift[c] = beta[c] - mean * sc;
}

// ---------------- Kernel 3: elementwise apply ----------------
// x is L3-resident after bn_stats (205.5 MB < 256 MiB Infinity Cache).
// Non-temporal store of out avoids evicting x mid-pass -> read side mostly L3.
__global__ void __launch_bounds__(256) bn_apply(const float* __restrict__ x,
                                                const float* __restrict__ scale,
                                                const float* __restrict__ shift,
                                                float* __restrict__ out) {
    const unsigned int i = blockIdx.x * 256u + threadIdx.x;   // float4 index, grid exact
    const unsigned int c = (i / (unsigned int)HW4_) & (C_ - 1u);
    vfloat4 v = ((const vfloat4*)x)[i];
    const float sc = scale[c];
    const float sh = shift[c];
    vfloat4 o;
    o.x = v.x * sc + sh;
    o.y = v.y * sc + sh;
    o.z = v.z * sc + sh;
    o.w = v.w * sc + sh;
    __builtin_nontemporal_store(o, (vfloat4*)out + i);
}

extern "C" void kernel_launch(void* const* d_in, const int* in_sizes, int n_in,
                              void* d_out, int out_size, void* d_ws, size_t ws_size,
                              hipStream_t stream) {
    const float* x     = (const float*)d_in[0];
    const float* gamma = (const float*)d_in[1];
    const float* beta  = (const float*)d_in[2];
    float* out = (float*)d_out;

    // workspace layout (floats): psum[C*NB] | psumsq[C*NB] | scale[C] | shift[C]
    float* psum   = (float*)d_ws;
    float* psumsq = psum + C_ * NB_;
    float* scale  = psumsq + C_ * NB_;
    float* shift  = scale + C_;

    bn_stats<<<C_ * NB_, 256, 0, stream>>>(x, psum, psumsq);
    bn_finalize<<<C_ / 64, 64, 0, stream>>>(psum, psumsq, gamma, beta, scale, shift);
    bn_apply<<<TOTAL4_ / 256u, 256, 0, stream>>>(x, scale, shift, out);
}